// Round 1
// baseline (390.808 us; speedup 1.0000x reference)
//
#include <hip/hip_runtime.h>
#include <hip/hip_bf16.h>

// Shapes
#define BB 128
#define LL 512
#define DD 300
#define HH 200
#define NEGBIG 1e12f

// ---------------------------------------------------------------------------
// Kernel 1: masked max-pool partials. Grid = B*8 (64-l chunks), block = 256.
// subj/obj kept where pos == 0 (reference: where(pos!=0, -1e12, h) then max).
// ---------------------------------------------------------------------------
__global__ __launch_bounds__(256) void pool_partial(
    const int* __restrict__ words, const int* __restrict__ spos,
    const int* __restrict__ opos, const float* __restrict__ tab,
    float* __restrict__ spart, float* __restrict__ opart) {
  int blk = blockIdx.x;
  int b = blk >> 3, ch = blk & 7;
  int l0 = ch * 64;
  int tid = threadIdx.x;
  __shared__ int wd[64];
  __shared__ int sm[64];
  __shared__ int om[64];
  if (tid < 64) {
    int l = l0 + tid;
    wd[tid] = words[b * LL + l];
    sm[tid] = spos[b * LL + l];
    om[tid] = opos[b * LL + l];
  }
  __syncthreads();
  int d0 = tid, d1 = tid + 256;
  bool has1 = (d1 < DD);
  float smax0 = -NEGBIG, smax1 = -NEGBIG, omax0 = -NEGBIG, omax1 = -NEGBIG;
  for (int i = 0; i < 64; ++i) {
    const float* row = tab + (size_t)wd[i] * DD;
    float v0 = row[d0];
    float v1 = has1 ? row[d1] : 0.f;
    bool su = (sm[i] == 0), ou = (om[i] == 0);
    if (su) { smax0 = fmaxf(smax0, v0); smax1 = fmaxf(smax1, v1); }
    if (ou) { omax0 = fmaxf(omax0, v0); omax1 = fmaxf(omax1, v1); }
  }
  size_t base = (size_t)(ch * BB + b) * DD;
  spart[base + d0] = smax0;
  opart[base + d0] = omax0;
  if (has1) { spart[base + d1] = smax1; opart[base + d1] = omax1; }
}

// ---------------------------------------------------------------------------
// Kernel 2: combine 8 pool partials. Grid = B, block = 320 (300 active).
// ---------------------------------------------------------------------------
__global__ __launch_bounds__(320) void pool_combine(
    const float* __restrict__ spart, const float* __restrict__ opart,
    float* __restrict__ semb, float* __restrict__ oemb) {
  int b = blockIdx.x, d = threadIdx.x;
  if (d >= DD) return;
  float s = -NEGBIG, o = -NEGBIG;
  for (int ch = 0; ch < 8; ++ch) {
    size_t base = (size_t)(ch * BB + b) * DD + d;
    s = fmaxf(s, spart[base]);
    o = fmaxf(o, opart[base]);
  }
  semb[(size_t)b * DD + d] = s;
  oemb[(size_t)b * DD + d] = o;
}

// ---------------------------------------------------------------------------
// Kernel 3: pre_h[b,h] = b1[h] + sum_d subj_emb[b,d] * w1[(300+d)*200+h]
// Grid = B, block = 256 (200 active).
// ---------------------------------------------------------------------------
__global__ __launch_bounds__(256) void preh_kernel(
    const float* __restrict__ semb, const float* __restrict__ w1,
    const float* __restrict__ b1, float* __restrict__ preh) {
  int b = blockIdx.x, tid = threadIdx.x;
  __shared__ float se[DD];
  for (int d = tid; d < DD; d += 256) se[d] = semb[(size_t)b * DD + d];
  __syncthreads();
  if (tid >= HH) return;
  float acc = b1[tid];
  for (int d = 0; d < DD; ++d) acc += se[d] * w1[(size_t)(DD + d) * HH + tid];
  preh[(size_t)b * HH + tid] = acc;
}

// ---------------------------------------------------------------------------
// Kernel 4: fused scores GEMM. [64 pos] x [300 K] x [200 H] per block,
// K-chunks of 30. score[b,l] = b2 + sum_h w2[h]*tanh(emb.w1[:,h] + pre_h[b,h])
// Grid = 1024 (B*8 tiles of 64 contiguous l), block = 256 (16 pos-grp x 16 h-grp).
// ---------------------------------------------------------------------------
__global__ __launch_bounds__(256) void scores_kernel(
    const int* __restrict__ words, const float* __restrict__ tab,
    const float* __restrict__ w1, const float* __restrict__ preh,
    const float* __restrict__ w2, const float* __restrict__ b2,
    float* __restrict__ scores) {
  int tile = blockIdx.x;
  int b = tile >> 3;
  int l0 = (tile & 7) * 64;
  int tid = threadIdx.x;

  __shared__ int wd[64];
  __shared__ float ebuf[64][31];    // K-chunk of 30, +1 pad (bank)
  __shared__ float wbuf[30][208];   // h padded to 208, pad cols zeroed

  if (tid < 64) wd[tid] = words[b * LL + l0 + tid];

  int tp = tid >> 4;   // 0..15: position group; positions tp, tp+16, tp+32, tp+48
  int th = tid & 15;   // 0..15: h group; h = th + 16*c, c = 0..12

  float acc[4][13];
#pragma unroll
  for (int a = 0; a < 4; ++a)
#pragma unroll
    for (int c = 0; c < 13; ++c) acc[a][c] = 0.f;

  int si = tid >> 2, sq = tid & 3;  // staging: 4 threads per emb row

  for (int kc = 0; kc < 10; ++kc) {
    int k0 = kc * 30;
    __syncthreads();
    {
      const float* row = tab + (size_t)wd[si] * DD + k0;
#pragma unroll
      for (int j = 0; j < 8; ++j) {
        int kl = sq * 8 + j;
        if (kl < 30) ebuf[si][kl] = row[kl];
      }
    }
    for (int n = tid; n < 30 * 208; n += 256) {
      int r = n / 208, c = n % 208;
      wbuf[r][c] = (c < HH) ? w1[(size_t)(k0 + r) * HH + c] : 0.f;
    }
    __syncthreads();
    for (int k = 0; k < 30; ++k) {
      float e0 = ebuf[tp][k];
      float e1 = ebuf[tp + 16][k];
      float e2 = ebuf[tp + 32][k];
      float e3 = ebuf[tp + 48][k];
#pragma unroll
      for (int c = 0; c < 13; ++c) {
        float wv = wbuf[k][th + 16 * c];
        acc[0][c] += e0 * wv;
        acc[1][c] += e1 * wv;
        acc[2][c] += e2 * wv;
        acc[3][c] += e3 * wv;
      }
    }
  }

  // epilogue: tanh, * w2, partial per position
  float part[4] = {0.f, 0.f, 0.f, 0.f};
#pragma unroll
  for (int c = 0; c < 13; ++c) {
    int h = th + 16 * c;
    if (h < HH) {
      float wv = w2[h];
      float ph = preh[(size_t)b * HH + h];
      part[0] += wv * tanhf(acc[0][c] + ph);
      part[1] += wv * tanhf(acc[1][c] + ph);
      part[2] += wv * tanhf(acc[2][c] + ph);
      part[3] += wv * tanhf(acc[3][c] + ph);
    }
  }
  // reduce across the 16 th-lanes (contiguous within a wave)
#pragma unroll
  for (int off = 8; off; off >>= 1) {
#pragma unroll
    for (int a = 0; a < 4; ++a) part[a] += __shfl_xor(part[a], off, 16);
  }
  if (th == 0) {
    float bb = b2[0];
#pragma unroll
    for (int a = 0; a < 4; ++a)
      scores[(size_t)b * LL + l0 + tp + 16 * a] = part[a] + bb;
  }
}

// ---------------------------------------------------------------------------
// Kernel 5: softmax over L=512 per batch row. Grid = B, block = 256.
// ---------------------------------------------------------------------------
__global__ __launch_bounds__(256) void softmax_kernel(
    const float* __restrict__ scores, float* __restrict__ attn) {
  int b = blockIdx.x, tid = threadIdx.x;
  __shared__ float red[16];
  float s0 = scores[(size_t)b * LL + tid];
  float s1 = scores[(size_t)b * LL + 256 + tid];
  float m = fmaxf(s0, s1);
#pragma unroll
  for (int off = 32; off; off >>= 1) m = fmaxf(m, __shfl_xor(m, off, 64));
  if ((tid & 63) == 0) red[tid >> 6] = m;
  __syncthreads();
  float M = fmaxf(fmaxf(red[0], red[1]), fmaxf(red[2], red[3]));
  float e0 = expf(s0 - M);
  float e1 = expf(s1 - M);
  float s = e0 + e1;
#pragma unroll
  for (int off = 32; off; off >>= 1) s += __shfl_xor(s, off, 64);
  if ((tid & 63) == 0) red[8 + (tid >> 6)] = s;
  __syncthreads();
  float S = red[8] + red[9] + red[10] + red[11];
  attn[(size_t)b * LL + tid] = e0 / S;
  attn[(size_t)b * LL + 256 + tid] = e1 / S;
}

// ---------------------------------------------------------------------------
// Kernel 6: PV partials: av[b,d] += attn[b,l] * emb[words[b,l], d]
// Grid = B*8, block = 256 (same chunking as pool_partial).
// ---------------------------------------------------------------------------
__global__ __launch_bounds__(256) void pv_partial(
    const int* __restrict__ words, const float* __restrict__ attn,
    const float* __restrict__ tab, float* __restrict__ avpart) {
  int blk = blockIdx.x;
  int b = blk >> 3, ch = blk & 7;
  int l0 = ch * 64;
  int tid = threadIdx.x;
  __shared__ int wd[64];
  __shared__ float at[64];
  if (tid < 64) {
    wd[tid] = words[b * LL + l0 + tid];
    at[tid] = attn[(size_t)b * LL + l0 + tid];
  }
  __syncthreads();
  int d0 = tid, d1 = tid + 256;
  bool has1 = (d1 < DD);
  float a0 = 0.f, a1 = 0.f;
  for (int i = 0; i < 64; ++i) {
    const float* row = tab + (size_t)wd[i] * DD;
    float w = at[i];
    a0 += w * row[d0];
    if (has1) a1 += w * row[d1];
  }
  size_t base = (size_t)(ch * BB + b) * DD;
  avpart[base + d0] = a0;
  if (has1) avpart[base + d1] = a1;
}

// ---------------------------------------------------------------------------
// Kernel 7: combine PV partials. Grid = B, block = 320.
// ---------------------------------------------------------------------------
__global__ __launch_bounds__(320) void pv_combine(
    const float* __restrict__ avpart, float* __restrict__ sattn) {
  int b = blockIdx.x, d = threadIdx.x;
  if (d >= DD) return;
  float s = 0.f;
  for (int ch = 0; ch < 8; ++ch) s += avpart[(size_t)(ch * BB + b) * DD + d];
  sattn[(size_t)b * DD + d] = s;
}

// ---------------------------------------------------------------------------
// Kernel 8: final MLP. x = [sattn, sattn, semb, oemb] (obj_attn == subj_attn,
// source bug preserved). out = relu(relu(x@mw1+mb1)@mw2+mb2). Grid=B, blk=256.
// ---------------------------------------------------------------------------
__global__ __launch_bounds__(256) void mlp_kernel(
    const float* __restrict__ sattn, const float* __restrict__ semb,
    const float* __restrict__ oemb, const float* __restrict__ mw1,
    const float* __restrict__ mb1, const float* __restrict__ mw2,
    const float* __restrict__ mb2, float* __restrict__ out) {
  int b = blockIdx.x, tid = threadIdx.x;
  __shared__ float x[4 * DD];
  __shared__ float h1[HH];
  for (int i = tid; i < 4 * DD; i += 256) {
    int seg = i / DD, r = i % DD;
    float v;
    if (seg <= 1) v = sattn[(size_t)b * DD + r];
    else if (seg == 2) v = semb[(size_t)b * DD + r];
    else v = oemb[(size_t)b * DD + r];
    x[i] = v;
  }
  __syncthreads();
  if (tid < HH) {
    float acc = mb1[tid];
    for (int k = 0; k < 4 * DD; ++k) acc += x[k] * mw1[(size_t)k * HH + tid];
    h1[tid] = fmaxf(acc, 0.f);
  }
  __syncthreads();
  if (tid < HH) {
    float acc = mb2[tid];
    for (int k = 0; k < HH; ++k) acc += h1[k] * mw2[(size_t)k * HH + tid];
    out[(size_t)b * HH + tid] = fmaxf(acc, 0.f);
  }
}

// ---------------------------------------------------------------------------
extern "C" void kernel_launch(void* const* d_in, const int* in_sizes, int n_in,
                              void* d_out, int out_size, void* d_ws, size_t ws_size,
                              hipStream_t stream) {
  const int* words   = (const int*)d_in[0];
  const int* spos    = (const int*)d_in[1];
  const int* opos    = (const int*)d_in[2];
  const float* tab   = (const float*)d_in[3];
  const float* w1    = (const float*)d_in[4];
  const float* b1    = (const float*)d_in[5];
  const float* w2    = (const float*)d_in[6];
  const float* b2    = (const float*)d_in[7];
  const float* mw1   = (const float*)d_in[8];
  const float* mb1   = (const float*)d_in[9];
  const float* mw2   = (const float*)d_in[10];
  const float* mb2   = (const float*)d_in[11];
  float* out = (float*)d_out;

  // workspace layout (floats)
  float* w = (float*)d_ws;
  const size_t SPART = (size_t)8 * BB * DD;   // 307200
  const size_t SEMBN = (size_t)BB * DD;       // 38400
  const size_t PREHN = (size_t)BB * HH;       // 25600
  const size_t SCN   = (size_t)BB * LL;       // 65536
  float* spart  = w;                  w += SPART;
  float* opart  = w;                  w += SPART;
  float* semb   = w;                  w += SEMBN;
  float* oemb   = w;                  w += SEMBN;
  float* preh   = w;                  w += PREHN;
  float* scores = w;                  w += SCN;
  float* attn   = w;                  w += SCN;
  float* avpart = w;                  w += SPART;
  float* sattn  = w;                  w += SEMBN;

  pool_partial<<<dim3(BB * 8), dim3(256), 0, stream>>>(words, spos, opos, tab, spart, opart);
  pool_combine<<<dim3(BB), dim3(320), 0, stream>>>(spart, opart, semb, oemb);
  preh_kernel<<<dim3(BB), dim3(256), 0, stream>>>(semb, w1, b1, preh);
  scores_kernel<<<dim3(BB * 8), dim3(256), 0, stream>>>(words, tab, w1, preh, w2, b2, scores);
  softmax_kernel<<<dim3(BB), dim3(256), 0, stream>>>(scores, attn);
  pv_partial<<<dim3(BB * 8), dim3(256), 0, stream>>>(words, attn, tab, avpart);
  pv_combine<<<dim3(BB), dim3(320), 0, stream>>>(avpart, sattn);
  mlp_kernel<<<dim3(BB), dim3(256), 0, stream>>>(sattn, semb, oemb, mw1, mb1, mw2, mb2, out);
}

// Round 2
// 286.750 us; speedup vs baseline: 1.3629x; 1.3629x over previous
//
#include <hip/hip_runtime.h>
#include <hip/hip_bf16.h>

#define BB 128
#define LL 512
#define DD 300
#define HH 200
#define VV 50000
#define KP 320           // K padded (10 chunks of 32)
#define HP 208           // H padded (13 tiles of 16)
#define NEGBIG 1e12f

typedef __attribute__((ext_vector_type(8))) short bf16x8;
typedef __attribute__((ext_vector_type(4))) float f32x4;

__device__ __forceinline__ float bf2f(unsigned short u) {
  union { unsigned int i; float f; } v; v.i = ((unsigned int)u) << 16; return v.f;
}
__device__ __forceinline__ unsigned short f2bf(float f) {
  union { float f; unsigned int i; } v; v.f = f;
  unsigned int r = v.i + 0x7FFFu + ((v.i >> 16) & 1u);  // RNE (finite inputs)
  return (unsigned short)(r >> 16);
}

// ---------------------------------------------------------------------------
// Prep 1: table fp32[V][300] -> bf16[V][320], zero-padded K tail.
// 300 = 75 float4 quads exactly; quads 75..79 are zeros.
// ---------------------------------------------------------------------------
__global__ __launch_bounds__(256) void prep_tab(
    const float* __restrict__ tab, unsigned short* __restrict__ tabbf) {
  const int total = VV * 80;
  for (int q = blockIdx.x * 256 + threadIdx.x; q < total; q += gridDim.x * 256) {
    int row = q / 80, c4 = (q - row * 80) * 4;
    ushort4 o;
    if (c4 < DD) {
      float4 v = *(const float4*)(tab + (size_t)row * DD + c4);
      o.x = f2bf(v.x); o.y = f2bf(v.y); o.z = f2bf(v.z); o.w = f2bf(v.w);
    } else {
      o.x = o.y = o.z = o.w = 0;
    }
    *(ushort4*)(tabbf + (size_t)row * KP + c4) = o;
  }
}

// ---------------------------------------------------------------------------
// Prep 2: w1 fp32[300][200] (prefs half) -> bf16 transposed [208][320], padded.
// ---------------------------------------------------------------------------
__global__ __launch_bounds__(256) void prep_w1t(
    const float* __restrict__ w1, unsigned short* __restrict__ w1t) {
  int q = blockIdx.x * 256 + threadIdx.x;  // grid covers 208*320 = 66560
  if (q >= HP * KP) return;
  int h = q / KP, k = q - h * KP;
  float v = (h < HH && k < DD) ? w1[(size_t)k * HH + h] : 0.f;
  w1t[q] = f2bf(v);
}

// ---------------------------------------------------------------------------
// Kernel: masked max-pool partials (bf16 table). Grid B*8, block 256.
// ---------------------------------------------------------------------------
__global__ __launch_bounds__(256) void pool_partial(
    const int* __restrict__ words, const int* __restrict__ spos,
    const int* __restrict__ opos, const unsigned short* __restrict__ tabbf,
    float* __restrict__ spart, float* __restrict__ opart) {
  int blk = blockIdx.x;
  int b = blk >> 3, ch = blk & 7, l0 = ch * 64;
  int tid = threadIdx.x;
  __shared__ int wd[64], sm[64], om[64];
  if (tid < 64) {
    wd[tid] = words[b * LL + l0 + tid];
    sm[tid] = spos[b * LL + l0 + tid];
    om[tid] = opos[b * LL + l0 + tid];
  }
  __syncthreads();
  if (tid >= 150) return;
  int d2 = tid * 2;
  float s0 = -NEGBIG, s1 = -NEGBIG, o0 = -NEGBIG, o1 = -NEGBIG;
  for (int i = 0; i < 64; ++i) {
    ushort2 uv = *(const ushort2*)(tabbf + (size_t)wd[i] * KP + d2);
    float v0 = bf2f(uv.x), v1 = bf2f(uv.y);
    if (sm[i] == 0) { s0 = fmaxf(s0, v0); s1 = fmaxf(s1, v1); }
    if (om[i] == 0) { o0 = fmaxf(o0, v0); o1 = fmaxf(o1, v1); }
  }
  size_t base = (size_t)(ch * BB + b) * DD + d2;
  *(float2*)(spart + base) = make_float2(s0, s1);
  *(float2*)(opart + base) = make_float2(o0, o1);
}

// ---------------------------------------------------------------------------
// Kernel: combine pool partials + fused preh. Grid B, block 320.
// preh[b,h] = b1[h] + sum_d semb[b,d] * w1[(300+d)*200+h]
// ---------------------------------------------------------------------------
__global__ __launch_bounds__(320) void combine_preh(
    const float* __restrict__ spart, const float* __restrict__ opart,
    const float* __restrict__ w1, const float* __restrict__ b1,
    float* __restrict__ semb, float* __restrict__ oemb,
    float* __restrict__ preh) {
  int b = blockIdx.x, t = threadIdx.x;
  __shared__ float se[DD];
  if (t < DD) {
    float s = -NEGBIG, o = -NEGBIG;
    for (int ch = 0; ch < 8; ++ch) {
      size_t base = (size_t)(ch * BB + b) * DD + t;
      s = fmaxf(s, spart[base]);
      o = fmaxf(o, opart[base]);
    }
    semb[(size_t)b * DD + t] = s;
    oemb[(size_t)b * DD + t] = o;
    se[t] = s;
  }
  __syncthreads();
  if (t < HH) {
    float acc = b1[t];
    for (int d = 0; d < DD; ++d) acc += se[d] * w1[(size_t)(DD + d) * HH + t];
    preh[(size_t)b * HH + t] = acc;
  }
}

// ---------------------------------------------------------------------------
// Kernel: scores via MFMA. Grid B*8 (64-pos tiles), block 256 (4 waves).
// Wave w owns positions [16w,16w+16); 13 n-tiles of 16 h; 10 k-chunks of 32.
// A frag: lane l reads tab_bf[wd[16w+(l&15)]][kc*32 + 8*(l>>4) .. +8]  (16B)
// B frag: lane l reads w1t[nt*16+(l&15)][kc*32 + 8*(l>>4) .. +8]      (16B)
// D: col(h-in-tile)=lane&15, row(pos-in-16)=4*(l>>4)+reg.
// Epilogue: score = b2 + sum_h w2[h]*tanh(acc + preh[b,h]); w2/preh padded 0.
// ---------------------------------------------------------------------------
__global__ __launch_bounds__(256) void scores_mfma(
    const int* __restrict__ words, const unsigned short* __restrict__ tabbf,
    const unsigned short* __restrict__ w1t, const float* __restrict__ preh,
    const float* __restrict__ w2, const float* __restrict__ b2,
    float* __restrict__ scores) {
  int tile = blockIdx.x;
  int b = tile >> 3, l0 = (tile & 7) * 64;
  int tid = threadIdx.x;
  int w = tid >> 6, lane = tid & 63;
  int lr = lane & 15, lq = lane >> 4;

  __shared__ int wd[64];
  if (tid < 64) wd[tid] = words[b * LL + l0 + tid];
  __syncthreads();

  int myrow = wd[w * 16 + lr];
  const unsigned short* arow = tabbf + (size_t)myrow * KP + lq * 8;
  const unsigned short* brow = w1t + (size_t)lr * KP + lq * 8;

  f32x4 acc[13];
#pragma unroll
  for (int nt = 0; nt < 13; ++nt) acc[nt] = (f32x4){0.f, 0.f, 0.f, 0.f};

  for (int kc = 0; kc < 10; ++kc) {
    bf16x8 a = *(const bf16x8*)(arow + kc * 32);
#pragma unroll
    for (int nt = 0; nt < 13; ++nt) {
      bf16x8 bf = *(const bf16x8*)(brow + (size_t)nt * 16 * KP + kc * 32);
      acc[nt] = __builtin_amdgcn_mfma_f32_16x16x32_bf16(a, bf, acc[nt], 0, 0, 0);
    }
  }

  // epilogue
  float w2v[13], ph[13];
#pragma unroll
  for (int nt = 0; nt < 13; ++nt) {
    int h = nt * 16 + lr;
    bool v = (h < HH);
    w2v[nt] = v ? w2[h] : 0.f;
    ph[nt] = v ? preh[(size_t)b * HH + h] : 0.f;
  }
  float part[4] = {0.f, 0.f, 0.f, 0.f};
#pragma unroll
  for (int nt = 0; nt < 13; ++nt) {
#pragma unroll
    for (int r = 0; r < 4; ++r)
      part[r] += w2v[nt] * tanhf(acc[nt][r] + ph[nt]);
  }
#pragma unroll
  for (int off = 8; off; off >>= 1) {
#pragma unroll
    for (int r = 0; r < 4; ++r) part[r] += __shfl_xor(part[r], off, 16);
  }
  if (lr == 0) {
    float bb = b2[0];
#pragma unroll
    for (int r = 0; r < 4; ++r) {
      int pos = l0 + w * 16 + lq * 4 + r;
      scores[(size_t)b * LL + pos] = part[r] + bb;
    }
  }
}

// ---------------------------------------------------------------------------
// Kernel: softmax over L=512. Grid B, block 256.
// ---------------------------------------------------------------------------
__global__ __launch_bounds__(256) void softmax_kernel(
    const float* __restrict__ scores, float* __restrict__ attn) {
  int b = blockIdx.x, tid = threadIdx.x;
  __shared__ float red[16];
  float s0 = scores[(size_t)b * LL + tid];
  float s1 = scores[(size_t)b * LL + 256 + tid];
  float m = fmaxf(s0, s1);
#pragma unroll
  for (int off = 32; off; off >>= 1) m = fmaxf(m, __shfl_xor(m, off, 64));
  if ((tid & 63) == 0) red[tid >> 6] = m;
  __syncthreads();
  float M = fmaxf(fmaxf(red[0], red[1]), fmaxf(red[2], red[3]));
  float e0 = expf(s0 - M);
  float e1 = expf(s1 - M);
  float s = e0 + e1;
#pragma unroll
  for (int off = 32; off; off >>= 1) s += __shfl_xor(s, off, 64);
  if ((tid & 63) == 0) red[8 + (tid >> 6)] = s;
  __syncthreads();
  float S = red[8] + red[9] + red[10] + red[11];
  attn[(size_t)b * LL + tid] = e0 / S;
  attn[(size_t)b * LL + 256 + tid] = e1 / S;
}

// ---------------------------------------------------------------------------
// Kernel: PV partials (bf16 table). Grid B*8, block 256.
// ---------------------------------------------------------------------------
__global__ __launch_bounds__(256) void pv_partial(
    const int* __restrict__ words, const float* __restrict__ attn,
    const unsigned short* __restrict__ tabbf, float* __restrict__ avpart) {
  int blk = blockIdx.x;
  int b = blk >> 3, ch = blk & 7, l0 = ch * 64;
  int tid = threadIdx.x;
  __shared__ int wd[64];
  __shared__ float at[64];
  if (tid < 64) {
    wd[tid] = words[b * LL + l0 + tid];
    at[tid] = attn[(size_t)b * LL + l0 + tid];
  }
  __syncthreads();
  if (tid >= 150) return;
  int d2 = tid * 2;
  float a0 = 0.f, a1 = 0.f;
  for (int i = 0; i < 64; ++i) {
    ushort2 uv = *(const ushort2*)(tabbf + (size_t)wd[i] * KP + d2);
    float wgt = at[i];
    a0 += wgt * bf2f(uv.x);
    a1 += wgt * bf2f(uv.y);
  }
  size_t base = (size_t)(ch * BB + b) * DD + d2;
  *(float2*)(avpart + base) = make_float2(a0, a1);
}

// ---------------------------------------------------------------------------
// Kernel: combine PV partials. Grid B, block 320.
// ---------------------------------------------------------------------------
__global__ __launch_bounds__(320) void pv_combine(
    const float* __restrict__ avpart, float* __restrict__ sattn) {
  int b = blockIdx.x, t = threadIdx.x;
  if (t >= DD) return;
  float s = 0.f;
  for (int ch = 0; ch < 8; ++ch) s += avpart[(size_t)(ch * BB + b) * DD + t];
  sattn[(size_t)b * DD + t] = s;
}

// ---------------------------------------------------------------------------
// Kernel: MLP layer-1 partials. Grid 64 = (bc 0..7)*(kc 0..7), block 256.
// x[b] = [sattn, sattn, semb, oemb] (source bug: obj_attn==subj_attn).
// Each block: 16 b x 200 h over a 150-k slice. 4x4 register tile/thread.
// ---------------------------------------------------------------------------
__global__ __launch_bounds__(256) void mlp1p(
    const float* __restrict__ sattn, const float* __restrict__ semb,
    const float* __restrict__ oemb, const float* __restrict__ mw1,
    float* __restrict__ p1) {
  int bc = blockIdx.x >> 3, kc = blockIdx.x & 7;
  int tid = threadIdx.x;
  __shared__ float xT[150][16];
  for (int idx = tid; idx < 2400; idx += 256) {
    int bb = idx & 15, kk = idx >> 4;
    int k = kc * 150 + kk, b = bc * 16 + bb;
    float v;
    if (k < 600) v = sattn[(size_t)b * DD + (k >= DD ? k - DD : k)];
    else if (k < 900) v = semb[(size_t)b * DD + (k - 600)];
    else v = oemb[(size_t)b * DD + (k - 900)];
    xT[kk][bb] = v;
  }
  __syncthreads();
  if (tid >= 200) return;
  int hq = tid % 50, bq = tid / 50;
  int h0 = hq * 4, bb0 = bq * 4;
  float acc[4][4] = {{0.f}};
  for (int kk = 0; kk < 150; ++kk) {
    float4 xv = *(const float4*)&xT[kk][bb0];
    float4 wv = *(const float4*)(mw1 + (size_t)(kc * 150 + kk) * HH + h0);
    float xa[4] = {xv.x, xv.y, xv.z, xv.w};
    float wa[4] = {wv.x, wv.y, wv.z, wv.w};
#pragma unroll
    for (int i = 0; i < 4; ++i)
#pragma unroll
      for (int j = 0; j < 4; ++j) acc[i][j] += xa[i] * wa[j];
  }
#pragma unroll
  for (int i = 0; i < 4; ++i) {
    float4 o = make_float4(acc[i][0], acc[i][1], acc[i][2], acc[i][3]);
    *(float4*)(p1 + ((size_t)kc * BB + bc * 16 + bb0 + i) * HH + h0) = o;
  }
}

// ---------------------------------------------------------------------------
// Kernel: MLP combine + relu + layer-2 + relu. Grid 8 (bc), block 256.
// ---------------------------------------------------------------------------
__global__ __launch_bounds__(256) void mlp2f(
    const float* __restrict__ p1, const float* __restrict__ mb1,
    const float* __restrict__ mw2, const float* __restrict__ mb2,
    float* __restrict__ out) {
  int bc = blockIdx.x, tid = threadIdx.x;
  __shared__ float h1T[HH][16];
  for (int idx = tid; idx < 3200; idx += 256) {
    int h = idx % HH, bb = idx / HH;
    float s = mb1[h];
    for (int kc = 0; kc < 8; ++kc)
      s += p1[((size_t)kc * BB + bc * 16 + bb) * HH + h];
    h1T[h][bb] = fmaxf(s, 0.f);
  }
  __syncthreads();
  if (tid >= 200) return;
  int hq = tid % 50, bq = tid / 50;
  int h0 = hq * 4, bb0 = bq * 4;
  float acc[4][4];
#pragma unroll
  for (int i = 0; i < 4; ++i)
#pragma unroll
    for (int j = 0; j < 4; ++j) acc[i][j] = mb2[h0 + j];
  for (int k = 0; k < HH; ++k) {
    float4 xv = *(const float4*)&h1T[k][bb0];
    float4 wv = *(const float4*)(mw2 + (size_t)k * HH + h0);
    float xa[4] = {xv.x, xv.y, xv.z, xv.w};
    float wa[4] = {wv.x, wv.y, wv.z, wv.w};
#pragma unroll
    for (int i = 0; i < 4; ++i)
#pragma unroll
      for (int j = 0; j < 4; ++j) acc[i][j] += xa[i] * wa[j];
  }
#pragma unroll
  for (int i = 0; i < 4; ++i) {
    float4 o = make_float4(fmaxf(acc[i][0], 0.f), fmaxf(acc[i][1], 0.f),
                           fmaxf(acc[i][2], 0.f), fmaxf(acc[i][3], 0.f));
    *(float4*)(out + (size_t)(bc * 16 + bb0 + i) * HH + h0) = o;
  }
}

// ---------------------------------------------------------------------------
extern "C" void kernel_launch(void* const* d_in, const int* in_sizes, int n_in,
                              void* d_out, int out_size, void* d_ws, size_t ws_size,
                              hipStream_t stream) {
  const int* words = (const int*)d_in[0];
  const int* spos  = (const int*)d_in[1];
  const int* opos  = (const int*)d_in[2];
  const float* tab = (const float*)d_in[3];
  const float* w1  = (const float*)d_in[4];
  const float* b1  = (const float*)d_in[5];
  const float* w2  = (const float*)d_in[6];
  const float* b2  = (const float*)d_in[7];
  const float* mw1 = (const float*)d_in[8];
  const float* mb1 = (const float*)d_in[9];
  const float* mw2 = (const float*)d_in[10];
  const float* mb2 = (const float*)d_in[11];
  float* out = (float*)d_out;

  // workspace carving (bytes)
  char* p = (char*)d_ws;
  unsigned short* tabbf = (unsigned short*)p; p += (size_t)VV * KP * 2;   // 32.0 MB
  unsigned short* w1t   = (unsigned short*)p; p += (size_t)HP * KP * 2;   // 133 KB
  float* spart  = (float*)p; p += (size_t)8 * BB * DD * 4;
  float* opart  = (float*)p; p += (size_t)8 * BB * DD * 4;
  float* avpart = (float*)p; p += (size_t)8 * BB * DD * 4;
  float* semb   = (float*)p; p += (size_t)BB * DD * 4;
  float* oemb   = (float*)p; p += (size_t)BB * DD * 4;
  float* sattn  = (float*)p; p += (size_t)BB * DD * 4;
  float* preh   = (float*)p; p += (size_t)BB * HH * 4;
  float* scores = (float*)p; p += (size_t)BB * LL * 4;
  float* attn   = (float*)p; p += (size_t)BB * LL * 4;
  float* p1     = (float*)p; p += (size_t)8 * BB * HH * 4;

  prep_tab<<<dim3(2048), dim3(256), 0, stream>>>(tab, tabbf);
  prep_w1t<<<dim3(260), dim3(256), 0, stream>>>(w1, w1t);
  pool_partial<<<dim3(BB * 8), dim3(256), 0, stream>>>(words, spos, opos, tabbf, spart, opart);
  combine_preh<<<dim3(BB), dim3(320), 0, stream>>>(spart, opart, w1, b1, semb, oemb, preh);
  scores_mfma<<<dim3(BB * 8), dim3(256), 0, stream>>>(words, tabbf, w1t, preh, w2, b2, scores);
  softmax_kernel<<<dim3(BB), dim3(256), 0, stream>>>(scores, attn);
  pv_partial<<<dim3(BB * 8), dim3(256), 0, stream>>>(words, attn, tabbf, avpart);
  pv_combine<<<dim3(BB), dim3(320), 0, stream>>>(avpart, sattn);
  mlp1p<<<dim3(64), dim3(256), 0, stream>>>(sattn, semb, oemb, mw1, p1);
  mlp2f<<<dim3(8), dim3(256), 0, stream>>>(p1, mb1, mw2, mb2, out);
}

// Round 3
// 235.886 us; speedup vs baseline: 1.6568x; 1.2156x over previous
//
#include <hip/hip_runtime.h>
#include <hip/hip_bf16.h>

#define BB 128
#define LL 512
#define DD 300
#define HH 200
#define VV 50000
#define KP 320           // K padded (10 chunks of 32)
#define NEGBIG 1e12f

typedef __attribute__((ext_vector_type(8))) short bf16x8;
typedef __attribute__((ext_vector_type(4))) float f32x4;

__device__ __forceinline__ float bf2f(unsigned short u) {
  union { unsigned int i; float f; } v; v.i = ((unsigned int)u) << 16; return v.f;
}
__device__ __forceinline__ unsigned short f2bf(float f) {
  union { float f; unsigned int i; } v; v.f = f;
  unsigned int r = v.i + 0x7FFFu + ((v.i >> 16) & 1u);  // RNE (finite inputs)
  return (unsigned short)(r >> 16);
}

typedef const __attribute__((address_space(1))) unsigned int ga_u32;
typedef __attribute__((address_space(3))) unsigned int lds_u32;
__device__ __forceinline__ void gl_lds16(const void* g, void* l) {
  __builtin_amdgcn_global_load_lds((ga_u32*)g, (lds_u32*)l, 16, 0, 0);
}

// ---------------------------------------------------------------------------
// Kernel 1: fused gather + bf16 convert + emb_bf materialize + pool partials.
// Blocks 0..1023: (b, ch) tiles of 64 rows. Blocks 1024..1063: w1s2 prep.
// w1s2[kc][row<256][c16s<4] = w1_prefs[k = kc*32 + ((c16s^s(row))*8)+j][row],
// s(row) = (row ^ (row>>2)) & 3  (bank swizzle baked in; zeros pad h>=200,k>=300)
// ---------------------------------------------------------------------------
__global__ __launch_bounds__(256) void gather_pool(
    const int* __restrict__ words, const int* __restrict__ spos,
    const int* __restrict__ opos, const float* __restrict__ tab,
    const float* __restrict__ w1,
    unsigned short* __restrict__ embbf, unsigned short* __restrict__ w1s2,
    float* __restrict__ spart, float* __restrict__ opart) {
  int blk = blockIdx.x;
  int tid = threadIdx.x;

  if (blk >= 1024) {
    // ---- w1s2 prep: 40 blocks x 256 threads = 10240 c16 units
    int u = (blk - 1024) * 256 + tid;
    int kc = u >> 10;
    int rem = u & 1023;
    int row = rem >> 2, c16 = rem & 3;
    int s = (row ^ (row >> 2)) & 3;
    int kb = kc * 32 + ((c16 ^ s) << 3);
    bf16x8 o;
#pragma unroll
    for (int j = 0; j < 8; ++j) {
      int k = kb + j;
      float v = (k < DD && row < HH) ? w1[(size_t)k * HH + row] : 0.f;
      o[j] = (short)f2bf(v);
    }
    *(bf16x8*)(w1s2 + (size_t)u * 8) = o;
    return;
  }

  int b = blk >> 3, ch = blk & 7, l0 = ch * 64;
  __shared__ int wd[64], sm[64], om[64];
  __shared__ unsigned short tile[64 * 328];   // row stride 328 (bank-friendly)
  if (tid < 64) {
    wd[tid] = words[b * LL + l0 + tid];
    sm[tid] = spos[b * LL + l0 + tid];
    om[tid] = opos[b * LL + l0 + tid];
  }
  __syncthreads();

  // gather + convert: 4 threads per row, 64B-coalesced float4 reads
  {
    int r = tid >> 2, qg = tid & 3;
    const float* srow = tab + (size_t)wd[r] * DD;
    unsigned short* trow = tile + r * 328;
#pragma unroll
    for (int i = 0; i < 19; ++i) {
      int q = qg + 4 * i;
      if (q < 75) {
        float4 v = *(const float4*)(srow + q * 4);
        ushort4 o;
        o.x = f2bf(v.x); o.y = f2bf(v.y); o.z = f2bf(v.z); o.w = f2bf(v.w);
        *(ushort4*)(trow + q * 4) = o;
      }
    }
    // zero-pad cols 300..327
    if (qg == 0) {
#pragma unroll
      for (int c = 300; c < 328; c += 4) {
        ushort4 z; z.x = z.y = z.z = z.w = 0;
        *(ushort4*)(trow + c) = z;
      }
    }
  }
  __syncthreads();

  // stream LDS tile -> emb_bf (linear [64][320] bf16 rows)
  {
    char* embdst = (char*)embbf + (size_t)(b * LL + l0) * 640;
#pragma unroll
    for (int j = 0; j < 10; ++j) {
      int g16 = j * 256 + tid;
      int row = g16 / 40, cb = g16 % 40;
      uint4 v = *(const uint4*)((const char*)tile + row * 656 + cb * 16);
      *(uint4*)(embdst + (size_t)g16 * 16) = v;
    }
  }

  // pool partials from LDS (keep where pos==0)
  if (tid < 150) {
    float s0 = -NEGBIG, s1 = -NEGBIG, o0 = -NEGBIG, o1 = -NEGBIG;
    for (int r = 0; r < 64; ++r) {
      unsigned int v = *(const unsigned int*)((const char*)tile + r * 656 + tid * 4);
      float v0 = bf2f((unsigned short)(v & 0xffff));
      float v1 = bf2f((unsigned short)(v >> 16));
      if (sm[r] == 0) { s0 = fmaxf(s0, v0); s1 = fmaxf(s1, v1); }
      if (om[r] == 0) { o0 = fmaxf(o0, v0); o1 = fmaxf(o1, v1); }
    }
    size_t base = (size_t)(ch * BB + b) * DD + tid * 2;
    *(float2*)(spart + base) = make_float2(s0, s1);
    *(float2*)(opart + base) = make_float2(o0, o1);
  }
}

// ---------------------------------------------------------------------------
// Kernel 2: combine pool partials + fused preh. Grid B, block 320.
// preh[b,h] = b1[h] + sum_d semb[b,d] * w1[(300+d)*200+h]
// ---------------------------------------------------------------------------
__global__ __launch_bounds__(320) void combine_preh(
    const float* __restrict__ spart, const float* __restrict__ opart,
    const float* __restrict__ w1, const float* __restrict__ b1,
    float* __restrict__ semb, float* __restrict__ oemb,
    float* __restrict__ preh) {
  int b = blockIdx.x, t = threadIdx.x;
  __shared__ float se[DD];
  if (t < DD) {
    float s = -NEGBIG, o = -NEGBIG;
    for (int ch = 0; ch < 8; ++ch) {
      size_t base = (size_t)(ch * BB + b) * DD + t;
      s = fmaxf(s, spart[base]);
      o = fmaxf(o, opart[base]);
    }
    semb[(size_t)b * DD + t] = s;
    oemb[(size_t)b * DD + t] = o;
    se[t] = s;
  }
  __syncthreads();
  if (t < HH) {
    float acc = b1[t];
    for (int d = 0; d < DD; ++d) acc += se[d] * w1[(size_t)(DD + d) * HH + t];
    preh[(size_t)b * HH + t] = acc;
  }
}

// ---------------------------------------------------------------------------
// Kernel 3: scores via MFMA, LDS-staged. Grid B*8 (64-pos tiles), block 256.
// A: full 64x320 tile staged once via global_load_lds, col16 XOR (row&7) swz.
// B: w1s2 chunk (16KB, pre-swizzled, chunk-major) double-buffered, 2-phase.
// ---------------------------------------------------------------------------
__global__ __launch_bounds__(256) void scores_mfma(
    const unsigned short* __restrict__ embbf,
    const unsigned short* __restrict__ w1s2, const float* __restrict__ preh,
    const float* __restrict__ w2, const float* __restrict__ b2,
    float* __restrict__ scores) {
  int tile = blockIdx.x;
  int b = tile >> 3, l0 = (tile & 7) * 64;
  int tid = threadIdx.x;
  int w = tid >> 6, lane = tid & 63;
  int lr = lane & 15, lq = lane >> 4;

  __shared__ unsigned short ldsA[64 * 320];        // 40960 B, swizzled
  __shared__ unsigned short ldsB[2][256 * 32];     // 2 x 16384 B

  const char* embbase = (const char*)embbf + (size_t)(b * LL + l0) * 640;
  int wbase16 = (w << 6);   // wave-uniform lane-0 16B-unit index offset

  // ---- prologue: stage A (10 instr/thread) + B chunk 0 (4 instr/thread)
#pragma unroll
  for (int j = 0; j < 10; ++j) {
    int d16 = j * 256 + tid;
    int row = d16 / 40, c = d16 % 40;
    const void* src = embbase + row * 640 + (c ^ (row & 7)) * 16;
    void* dst = (char*)ldsA + (size_t)(j * 256 + wbase16) * 16;
    gl_lds16(src, dst);
  }
  {
    const char* srcb = (const char*)w1s2;  // kc = 0
#pragma unroll
    for (int j = 0; j < 4; ++j)
      gl_lds16(srcb + (size_t)(j * 256 + tid) * 16,
               (char*)&ldsB[0][0] + (size_t)(j * 256 + wbase16) * 16);
  }
  __syncthreads();   // drains vmcnt(0) + barrier

  f32x4 acc[13];
#pragma unroll
  for (int nt = 0; nt < 13; ++nt) acc[nt] = (f32x4){0.f, 0.f, 0.f, 0.f};

  int slr = (lr ^ (lr >> 2)) & 3;
  const char* aAddr = (const char*)ldsA + (w * 16 + lr) * 640;
  int cur = 0;
  for (int kc = 0; kc < 10; ++kc) {
    if (kc < 9) {   // stage next chunk into the other buffer
      const char* srcb = (const char*)w1s2 + (size_t)(kc + 1) * 16384;
#pragma unroll
      for (int j = 0; j < 4; ++j)
        gl_lds16(srcb + (size_t)(j * 256 + tid) * 16,
                 (char*)&ldsB[cur ^ 1][0] + (size_t)(j * 256 + wbase16) * 16);
    }
    bf16x8 a = *(const bf16x8*)(aAddr + (((kc * 4 + lq) ^ (lr & 7)) * 16));
    const char* bbase = (const char*)&ldsB[cur][0] + lr * 64 + ((lq ^ slr) * 16);
#pragma unroll
    for (int nt = 0; nt < 13; ++nt) {
      bf16x8 bv = *(const bf16x8*)(bbase + nt * 16 * 64);
      acc[nt] = __builtin_amdgcn_mfma_f32_16x16x32_bf16(a, bv, acc[nt], 0, 0, 0);
    }
    __syncthreads();   // vmcnt(0) + lgkmcnt(0) + barrier: next buffer ready
    cur ^= 1;
  }

  // ---- epilogue: score = b2 + sum_h w2[h]*tanh(acc + preh[b,h])
  float w2v[13], ph[13];
#pragma unroll
  for (int nt = 0; nt < 13; ++nt) {
    int h = nt * 16 + lr;
    bool v = (h < HH);
    w2v[nt] = v ? w2[h] : 0.f;
    ph[nt] = v ? preh[(size_t)b * HH + h] : 0.f;
  }
  float part[4] = {0.f, 0.f, 0.f, 0.f};
#pragma unroll
  for (int nt = 0; nt < 13; ++nt) {
#pragma unroll
    for (int r = 0; r < 4; ++r)
      part[r] += w2v[nt] * tanhf(acc[nt][r] + ph[nt]);
  }
#pragma unroll
  for (int off = 8; off; off >>= 1) {
#pragma unroll
    for (int r = 0; r < 4; ++r) part[r] += __shfl_xor(part[r], off, 16);
  }
  if (lr == 0) {
    float bb = b2[0];
#pragma unroll
    for (int r = 0; r < 4; ++r) {
      int pos = l0 + w * 16 + lq * 4 + r;
      scores[(size_t)b * LL + pos] = part[r] + bb;
    }
  }
}

// ---------------------------------------------------------------------------
// Kernel 4: fused softmax + PV partials. Grid B*8, block 256.
// Each block recomputes the full row softmax stats (cheap), then accumulates
// its 64-row slice of attn-weighted emb_bf (streaming, coalesced).
// ---------------------------------------------------------------------------
__global__ __launch_bounds__(256) void pv_sm(
    const float* __restrict__ scores, const unsigned short* __restrict__ embbf,
    float* __restrict__ avpart) {
  int blk = blockIdx.x;
  int b = blk >> 3, ch = blk & 7, l0 = ch * 64;
  int tid = threadIdx.x;
  __shared__ float red[16];
  __shared__ float at[64];

  float s0 = scores[(size_t)b * LL + tid];
  float s1 = scores[(size_t)b * LL + 256 + tid];
  float m = fmaxf(s0, s1);
#pragma unroll
  for (int off = 32; off; off >>= 1) m = fmaxf(m, __shfl_xor(m, off, 64));
  if ((tid & 63) == 0) red[tid >> 6] = m;
  __syncthreads();
  float M = fmaxf(fmaxf(red[0], red[1]), fmaxf(red[2], red[3]));
  float e = expf(s0 - M) + expf(s1 - M);
#pragma unroll
  for (int off = 32; off; off >>= 1) e += __shfl_xor(e, off, 64);
  if ((tid & 63) == 0) red[8 + (tid >> 6)] = e;
  __syncthreads();
  float S = red[8] + red[9] + red[10] + red[11];
  if (tid < 64) at[tid] = expf(scores[(size_t)b * LL + l0 + tid] - M) / S;
  __syncthreads();

  if (tid >= 150) return;
  const char* base = (const char*)embbf + (size_t)(b * LL + l0) * 640 + tid * 4;
  float a0 = 0.f, a1 = 0.f;
  for (int r = 0; r < 64; ++r) {
    unsigned int v = *(const unsigned int*)(base + (size_t)r * 640);
    float wgt = at[r];
    a0 += wgt * bf2f((unsigned short)(v & 0xffff));
    a1 += wgt * bf2f((unsigned short)(v >> 16));
  }
  size_t obase = (size_t)(ch * BB + b) * DD + tid * 2;
  *(float2*)(avpart + obase) = make_float2(a0, a1);
}

// ---------------------------------------------------------------------------
// Kernel 5: fused MLP (combine PV partials + layer1 + relu + layer2 + relu).
// Grid 32 (4 b each), block 256. x = [sattn, sattn, semb, oemb] (source bug).
// ---------------------------------------------------------------------------
__global__ __launch_bounds__(256) void mlp_fused(
    const float* __restrict__ avpart, const float* __restrict__ semb,
    const float* __restrict__ oemb, const float* __restrict__ mw1,
    const float* __restrict__ mb1, const float* __restrict__ mw2,
    const float* __restrict__ mb2, float* __restrict__ out) {
  int b0 = blockIdx.x * 4;
  int tid = threadIdx.x;
  __shared__ float x[4][1200];
  __shared__ float h1[4][HH];

  for (int idx = tid; idx < 4800; idx += 256) {
    int bb = idx / 1200, k = idx - bb * 1200;
    int b = b0 + bb;
    float v;
    if (k < 600) {
      int d = (k >= DD) ? k - DD : k;
      v = 0.f;
#pragma unroll
      for (int chh = 0; chh < 8; ++chh)
        v += avpart[(size_t)(chh * BB + b) * DD + d];
    } else if (k < 900) {
      v = semb[(size_t)b * DD + (k - 600)];
    } else {
      v = oemb[(size_t)b * DD + (k - 900)];
    }
    x[bb][k] = v;
  }
  __syncthreads();

  if (tid < HH) {
    float acc[4];
#pragma unroll
    for (int bb = 0; bb < 4; ++bb) acc[bb] = mb1[tid];
    for (int k = 0; k < 1200; ++k) {
      float wv = mw1[(size_t)k * HH + tid];
#pragma unroll
      for (int bb = 0; bb < 4; ++bb) acc[bb] += x[bb][k] * wv;
    }
#pragma unroll
    for (int bb = 0; bb < 4; ++bb) h1[bb][tid] = fmaxf(acc[bb], 0.f);
  }
  __syncthreads();
  if (tid < HH) {
    float acc[4];
#pragma unroll
    for (int bb = 0; bb < 4; ++bb) acc[bb] = mb2[tid];
    for (int k = 0; k < HH; ++k) {
      float wv = mw2[(size_t)k * HH + tid];
#pragma unroll
      for (int bb = 0; bb < 4; ++bb) acc[bb] += h1[bb][k] * wv;
    }
#pragma unroll
    for (int bb = 0; bb < 4; ++bb)
      out[(size_t)(b0 + bb) * HH + tid] = fmaxf(acc[bb], 0.f);
  }
}

// ---------------------------------------------------------------------------
extern "C" void kernel_launch(void* const* d_in, const int* in_sizes, int n_in,
                              void* d_out, int out_size, void* d_ws, size_t ws_size,
                              hipStream_t stream) {
  const int* words = (const int*)d_in[0];
  const int* spos  = (const int*)d_in[1];
  const int* opos  = (const int*)d_in[2];
  const float* tab = (const float*)d_in[3];
  const float* w1  = (const float*)d_in[4];
  const float* b1  = (const float*)d_in[5];
  const float* w2  = (const float*)d_in[6];
  const float* b2  = (const float*)d_in[7];
  const float* mw1 = (const float*)d_in[8];
  const float* mb1 = (const float*)d_in[9];
  const float* mw2 = (const float*)d_in[10];
  const float* mb2 = (const float*)d_in[11];
  float* out = (float*)d_out;

  // workspace carving (bytes)
  char* p = (char*)d_ws;
  unsigned short* embbf = (unsigned short*)p; p += (size_t)BB * LL * KP * 2;  // 41.9 MB
  unsigned short* w1s2  = (unsigned short*)p; p += (size_t)10 * 256 * 4 * 16; // 160 KB
  float* spart  = (float*)p; p += (size_t)8 * BB * DD * 4;
  float* opart  = (float*)p; p += (size_t)8 * BB * DD * 4;
  float* avpart = (float*)p; p += (size_t)8 * BB * DD * 4;
  float* semb   = (float*)p; p += (size_t)BB * DD * 4;
  float* oemb   = (float*)p; p += (size_t)BB * DD * 4;
  float* preh   = (float*)p; p += (size_t)BB * HH * 4;
  float* scores = (float*)p; p += (size_t)BB * LL * 4;

  gather_pool<<<dim3(1064), dim3(256), 0, stream>>>(
      words, spos, opos, tab, w1, embbf, w1s2, spart, opart);
  combine_preh<<<dim3(BB), dim3(320), 0, stream>>>(
      spart, opart, w1, b1, semb, oemb, preh);
  scores_mfma<<<dim3(BB * 8), dim3(256), 0, stream>>>(
      embbf, w1s2, preh, w2, b2, scores);
  pv_sm<<<dim3(BB * 8), dim3(256), 0, stream>>>(scores, embbf, avpart);
  mlp_fused<<<dim3(32), dim3(256), 0, stream>>>(
      avpart, semb, oemb, mw1, mb1, mw2, mb2, out);
}

// Round 4
// 206.814 us; speedup vs baseline: 1.8897x; 1.1406x over previous
//
#include <hip/hip_runtime.h>
#include <hip/hip_bf16.h>

#define BB 128
#define LL 512
#define DD 300
#define HH 200
#define VV 50000
#define KP 320           // K padded (10 chunks of 32)
#define NEGBIG 1e12f

typedef __attribute__((ext_vector_type(8))) short bf16x8;
typedef __attribute__((ext_vector_type(4))) float f32x4;

__device__ __forceinline__ float bf2f(unsigned short u) {
  union { unsigned int i; float f; } v; v.i = ((unsigned int)u) << 16; return v.f;
}
__device__ __forceinline__ unsigned short f2bf(float f) {
  union { float f; unsigned int i; } v; v.f = f;
  unsigned int r = v.i + 0x7FFFu + ((v.i >> 16) & 1u);  // RNE (finite inputs)
  return (unsigned short)(r >> 16);
}

typedef const __attribute__((address_space(1))) unsigned int ga_u32;
typedef __attribute__((address_space(3))) unsigned int lds_u32;
__device__ __forceinline__ void gl_lds16(const void* g, void* l) {
  __builtin_amdgcn_global_load_lds((ga_u32*)g, (lds_u32*)l, 16, 0, 0);
}

// ---------------------------------------------------------------------------
// Kernel 1: fused gather + bf16 convert + emb_bf materialize + pool partials.
// Blocks 0..1023: (b, ch) tiles of 64 rows. Blocks 1024..1063: w1s2 prep.
// Blocks 1064..1767: mw1eff prep (mw1eff[k] = mw1[k]+mw1[300+k] k<300;
//                    = mw1[300+k] k in [300,600); = mw1[600+k-600+300]... see below)
// ---------------------------------------------------------------------------
__global__ __launch_bounds__(256) void gather_pool(
    const int* __restrict__ words, const int* __restrict__ spos,
    const int* __restrict__ opos, const float* __restrict__ tab,
    const float* __restrict__ w1, const float* __restrict__ mw1,
    unsigned short* __restrict__ embbf, unsigned short* __restrict__ w1s2,
    float* __restrict__ mw1eff,
    float* __restrict__ spart, float* __restrict__ opart) {
  int blk = blockIdx.x;
  int tid = threadIdx.x;

  if (blk >= 1064) {
    // ---- mw1eff prep: eff-K = 900 (sattn 0..299, semb 300..599, oemb 600..899)
    int idx = (blk - 1064) * 256 + tid;
    if (idx < 900 * HH) {
      int k = idx / HH, h = idx - k * HH;
      float v;
      if (k < 300) v = mw1[(size_t)k * HH + h] + mw1[(size_t)(300 + k) * HH + h];
      else if (k < 600) v = mw1[(size_t)(k + 300) * HH + h];   // semb region
      else v = mw1[(size_t)(k + 300) * HH + h];                 // oemb region
      mw1eff[idx] = v;
    }
    return;
  }
  if (blk >= 1024) {
    // ---- w1s2 prep: 40 blocks x 256 threads = 10240 c16 units
    int u = (blk - 1024) * 256 + tid;
    int kc = u >> 10;
    int rem = u & 1023;
    int row = rem >> 2, c16 = rem & 3;
    int s = (row ^ (row >> 2)) & 3;
    int kb = kc * 32 + ((c16 ^ s) << 3);
    bf16x8 o;
#pragma unroll
    for (int j = 0; j < 8; ++j) {
      int k = kb + j;
      float v = (k < DD && row < HH) ? w1[(size_t)k * HH + row] : 0.f;
      o[j] = (short)f2bf(v);
    }
    *(bf16x8*)(w1s2 + (size_t)u * 8) = o;
    return;
  }

  int b = blk >> 3, ch = blk & 7, l0 = ch * 64;
  __shared__ int wd[64], sm[64], om[64];
  __shared__ unsigned short tile[64 * 328];   // row stride 328 (bank-friendly)
  if (tid < 64) {
    wd[tid] = words[b * LL + l0 + tid];
    sm[tid] = spos[b * LL + l0 + tid];
    om[tid] = opos[b * LL + l0 + tid];
  }
  __syncthreads();

  // gather + convert: 4 threads per row, 64B-coalesced float4 reads
  {
    int r = tid >> 2, qg = tid & 3;
    const float* srow = tab + (size_t)wd[r] * DD;
    unsigned short* trow = tile + r * 328;
#pragma unroll
    for (int i = 0; i < 19; ++i) {
      int q = qg + 4 * i;
      if (q < 75) {
        float4 v = *(const float4*)(srow + q * 4);
        ushort4 o;
        o.x = f2bf(v.x); o.y = f2bf(v.y); o.z = f2bf(v.z); o.w = f2bf(v.w);
        *(ushort4*)(trow + q * 4) = o;
      }
    }
    // zero-pad cols 300..327
    if (qg == 0) {
#pragma unroll
      for (int c = 300; c < 328; c += 4) {
        ushort4 z; z.x = z.y = z.z = z.w = 0;
        *(ushort4*)(trow + c) = z;
      }
    }
  }
  __syncthreads();

  // stream LDS tile -> emb_bf (linear [64][320] bf16 rows)
  {
    char* embdst = (char*)embbf + (size_t)(b * LL + l0) * 640;
#pragma unroll
    for (int j = 0; j < 10; ++j) {
      int g16 = j * 256 + tid;
      int row = g16 / 40, cb = g16 % 40;
      uint4 v = *(const uint4*)((const char*)tile + row * 656 + cb * 16);
      *(uint4*)(embdst + (size_t)g16 * 16) = v;
    }
  }

  // pool partials from LDS (keep where pos==0)
  if (tid < 150) {
    float s0 = -NEGBIG, s1 = -NEGBIG, o0 = -NEGBIG, o1 = -NEGBIG;
    for (int r = 0; r < 64; ++r) {
      unsigned int v = *(const unsigned int*)((const char*)tile + r * 656 + tid * 4);
      float v0 = bf2f((unsigned short)(v & 0xffff));
      float v1 = bf2f((unsigned short)(v >> 16));
      if (sm[r] == 0) { s0 = fmaxf(s0, v0); s1 = fmaxf(s1, v1); }
      if (om[r] == 0) { o0 = fmaxf(o0, v0); o1 = fmaxf(o1, v1); }
    }
    size_t base = (size_t)(ch * BB + b) * DD + tid * 2;
    *(float2*)(spart + base) = make_float2(s0, s1);
    *(float2*)(opart + base) = make_float2(o0, o1);
  }
}

// ---------------------------------------------------------------------------
// Kernel 2: combine pool partials + fused preh. Grid B, block 320.
// preh[b,h] = b1[h] + sum_d semb[b,d] * w1[(300+d)*200+h]
// ---------------------------------------------------------------------------
__global__ __launch_bounds__(320) void combine_preh(
    const float* __restrict__ spart, const float* __restrict__ opart,
    const float* __restrict__ w1, const float* __restrict__ b1,
    float* __restrict__ semb, float* __restrict__ oemb,
    float* __restrict__ preh) {
  int b = blockIdx.x, t = threadIdx.x;
  __shared__ float se[DD];
  if (t < DD) {
    float s = -NEGBIG, o = -NEGBIG;
    for (int ch = 0; ch < 8; ++ch) {
      size_t base = (size_t)(ch * BB + b) * DD + t;
      s = fmaxf(s, spart[base]);
      o = fmaxf(o, opart[base]);
    }
    semb[(size_t)b * DD + t] = s;
    oemb[(size_t)b * DD + t] = o;
    se[t] = s;
  }
  __syncthreads();
  if (t < HH) {
    const float* w1b = w1 + (size_t)DD * HH + t;
    float acc = b1[t];
#pragma unroll 10
    for (int d = 0; d < DD; ++d) acc += se[d] * w1b[(size_t)d * HH];
    preh[(size_t)b * HH + t] = acc;
  }
}

// ---------------------------------------------------------------------------
// Kernel 3: scores via MFMA, LDS-staged. Grid B*8 (64-pos tiles), block 256.
// A: full 64x320 tile staged once via global_load_lds, col16 XOR (row&7) swz.
// B: w1s2 chunk (16KB, pre-swizzled, chunk-major) double-buffered, 2-phase.
// ---------------------------------------------------------------------------
__global__ __launch_bounds__(256) void scores_mfma(
    const unsigned short* __restrict__ embbf,
    const unsigned short* __restrict__ w1s2, const float* __restrict__ preh,
    const float* __restrict__ w2, const float* __restrict__ b2,
    float* __restrict__ scores) {
  int tile = blockIdx.x;
  int b = tile >> 3, l0 = (tile & 7) * 64;
  int tid = threadIdx.x;
  int w = tid >> 6, lane = tid & 63;
  int lr = lane & 15, lq = lane >> 4;

  __shared__ unsigned short ldsA[64 * 320];        // 40960 B, swizzled
  __shared__ unsigned short ldsB[2][256 * 32];     // 2 x 16384 B

  const char* embbase = (const char*)embbf + (size_t)(b * LL + l0) * 640;
  int wbase16 = (w << 6);   // wave-uniform lane-0 16B-unit index offset

  // ---- prologue: stage A (10 instr/thread) + B chunk 0 (4 instr/thread)
#pragma unroll
  for (int j = 0; j < 10; ++j) {
    int d16 = j * 256 + tid;
    int row = d16 / 40, c = d16 % 40;
    const void* src = embbase + row * 640 + (c ^ (row & 7)) * 16;
    void* dst = (char*)ldsA + (size_t)(j * 256 + wbase16) * 16;
    gl_lds16(src, dst);
  }
  {
    const char* srcb = (const char*)w1s2;  // kc = 0
#pragma unroll
    for (int j = 0; j < 4; ++j)
      gl_lds16(srcb + (size_t)(j * 256 + tid) * 16,
               (char*)&ldsB[0][0] + (size_t)(j * 256 + wbase16) * 16);
  }
  __syncthreads();   // drains vmcnt(0) + barrier

  f32x4 acc[13];
#pragma unroll
  for (int nt = 0; nt < 13; ++nt) acc[nt] = (f32x4){0.f, 0.f, 0.f, 0.f};

  int slr = (lr ^ (lr >> 2)) & 3;
  const char* aAddr = (const char*)ldsA + (w * 16 + lr) * 640;
  int cur = 0;
  for (int kc = 0; kc < 10; ++kc) {
    if (kc < 9) {   // stage next chunk into the other buffer
      const char* srcb = (const char*)w1s2 + (size_t)(kc + 1) * 16384;
#pragma unroll
      for (int j = 0; j < 4; ++j)
        gl_lds16(srcb + (size_t)(j * 256 + tid) * 16,
                 (char*)&ldsB[cur ^ 1][0] + (size_t)(j * 256 + wbase16) * 16);
    }
    bf16x8 a = *(const bf16x8*)(aAddr + (((kc * 4 + lq) ^ (lr & 7)) * 16));
    const char* bbase = (const char*)&ldsB[cur][0] + lr * 64 + ((lq ^ slr) * 16);
#pragma unroll
    for (int nt = 0; nt < 13; ++nt) {
      bf16x8 bv = *(const bf16x8*)(bbase + nt * 16 * 64);
      acc[nt] = __builtin_amdgcn_mfma_f32_16x16x32_bf16(a, bv, acc[nt], 0, 0, 0);
    }
    __syncthreads();   // vmcnt(0) + lgkmcnt(0) + barrier: next buffer ready
    cur ^= 1;
  }

  // ---- epilogue: score = b2 + sum_h w2[h]*tanh(acc + preh[b,h])
  float w2v[13], ph[13];
#pragma unroll
  for (int nt = 0; nt < 13; ++nt) {
    int h = nt * 16 + lr;
    bool v = (h < HH);
    w2v[nt] = v ? w2[h] : 0.f;
    ph[nt] = v ? preh[(size_t)b * HH + h] : 0.f;
  }
  float part[4] = {0.f, 0.f, 0.f, 0.f};
#pragma unroll
  for (int nt = 0; nt < 13; ++nt) {
#pragma unroll
    for (int r = 0; r < 4; ++r)
      part[r] += w2v[nt] * tanhf(acc[nt][r] + ph[nt]);
  }
#pragma unroll
  for (int off = 8; off; off >>= 1) {
#pragma unroll
    for (int r = 0; r < 4; ++r) part[r] += __shfl_xor(part[r], off, 16);
  }
  if (lr == 0) {
    float bb = b2[0];
#pragma unroll
    for (int r = 0; r < 4; ++r) {
      int pos = l0 + w * 16 + lq * 4 + r;
      scores[(size_t)b * LL + pos] = part[r] + bb;
    }
  }
}

// ---------------------------------------------------------------------------
// Kernel 4: fused softmax + PV partials. Grid B*8, block 256.
// ---------------------------------------------------------------------------
__global__ __launch_bounds__(256) void pv_sm(
    const float* __restrict__ scores, const unsigned short* __restrict__ embbf,
    float* __restrict__ avpart) {
  int blk = blockIdx.x;
  int b = blk >> 3, ch = blk & 7, l0 = ch * 64;
  int tid = threadIdx.x;
  __shared__ float red[16];
  __shared__ float at[64];

  float s0 = scores[(size_t)b * LL + tid];
  float s1 = scores[(size_t)b * LL + 256 + tid];
  float m = fmaxf(s0, s1);
#pragma unroll
  for (int off = 32; off; off >>= 1) m = fmaxf(m, __shfl_xor(m, off, 64));
  if ((tid & 63) == 0) red[tid >> 6] = m;
  __syncthreads();
  float M = fmaxf(fmaxf(red[0], red[1]), fmaxf(red[2], red[3]));
  float e = expf(s0 - M) + expf(s1 - M);
#pragma unroll
  for (int off = 32; off; off >>= 1) e += __shfl_xor(e, off, 64);
  if ((tid & 63) == 0) red[8 + (tid >> 6)] = e;
  __syncthreads();
  float S = red[8] + red[9] + red[10] + red[11];
  if (tid < 64) at[tid] = expf(scores[(size_t)b * LL + l0 + tid] - M) / S;
  __syncthreads();

  if (tid >= 150) return;
  const char* base = (const char*)embbf + (size_t)(b * LL + l0) * 640 + tid * 4;
  float a0 = 0.f, a1 = 0.f;
  for (int r = 0; r < 64; ++r) {
    unsigned int v = *(const unsigned int*)(base + (size_t)r * 640);
    float wgt = at[r];
    a0 += wgt * bf2f((unsigned short)(v & 0xffff));
    a1 += wgt * bf2f((unsigned short)(v >> 16));
  }
  size_t obase = (size_t)(ch * BB + b) * DD + tid * 2;
  *(float2*)(avpart + obase) = make_float2(a0, a1);
}

// ---------------------------------------------------------------------------
// Kernel 5: MLP layer-1 partials over mw1eff (eff-K = 900).
// Grid 288 = (bc 0..15)*(kc 0..17), block 256. Each block: 8 b x 200 h x 50 k.
// x_eff = [sattn(300), semb(300), oemb(300)]; sattn combined from avpart here.
// ---------------------------------------------------------------------------
__global__ __launch_bounds__(256) void mlp1p(
    const float* __restrict__ avpart, const float* __restrict__ semb,
    const float* __restrict__ oemb, const float* __restrict__ mw1eff,
    float* __restrict__ p1) {
  int bc = blockIdx.x / 18, kc = blockIdx.x % 18;
  int tid = threadIdx.x;
  __shared__ float xT[50][8];
  for (int idx = tid; idx < 400; idx += 256) {
    int bb = idx & 7, kk = idx >> 3;
    int k = kc * 50 + kk;
    int b = bc * 8 + bb;
    int reg = k / 300, d = k - reg * 300;
    float v;
    if (reg == 0) {
      v = 0.f;
#pragma unroll
      for (int chh = 0; chh < 8; ++chh)
        v += avpart[(size_t)(chh * BB + b) * DD + d];
    } else if (reg == 1) {
      v = semb[(size_t)b * DD + d];
    } else {
      v = oemb[(size_t)b * DD + d];
    }
    xT[kk][bb] = v;
  }
  __syncthreads();
  if (tid >= HH) return;
  const float* wp = mw1eff + (size_t)(kc * 50) * HH + tid;
  float acc[8] = {0.f, 0.f, 0.f, 0.f, 0.f, 0.f, 0.f, 0.f};
#pragma unroll 5
  for (int kk = 0; kk < 50; ++kk) {
    float wv = wp[(size_t)kk * HH];
#pragma unroll
    for (int bb = 0; bb < 8; ++bb) acc[bb] += xT[kk][bb] * wv;
  }
#pragma unroll
  for (int bb = 0; bb < 8; ++bb)
    p1[((size_t)kc * BB + bc * 8 + bb) * HH + tid] = acc[bb];
}

// ---------------------------------------------------------------------------
// Kernel 6: MLP combine + relu + layer-2 + relu. Grid B (one b each), blk 256.
// ---------------------------------------------------------------------------
__global__ __launch_bounds__(256) void mlp2f(
    const float* __restrict__ p1, const float* __restrict__ mb1,
    const float* __restrict__ mw2, const float* __restrict__ mb2,
    float* __restrict__ out) {
  int b = blockIdx.x, tid = threadIdx.x;
  __shared__ float h1[HH];
  if (tid < HH) {
    float s = mb1[tid];
#pragma unroll
    for (int kc = 0; kc < 18; ++kc)
      s += p1[((size_t)kc * BB + b) * HH + tid];
    h1[tid] = fmaxf(s, 0.f);
  }
  __syncthreads();
  if (tid >= HH) return;
  const float* wp = mw2 + tid;
  float acc = mb2[tid];
#pragma unroll 8
  for (int k = 0; k < HH; ++k) acc += h1[k] * wp[(size_t)k * HH];
  out[(size_t)b * HH + tid] = fmaxf(acc, 0.f);
}

// ---------------------------------------------------------------------------
extern "C" void kernel_launch(void* const* d_in, const int* in_sizes, int n_in,
                              void* d_out, int out_size, void* d_ws, size_t ws_size,
                              hipStream_t stream) {
  const int* words = (const int*)d_in[0];
  const int* spos  = (const int*)d_in[1];
  const int* opos  = (const int*)d_in[2];
  const float* tab = (const float*)d_in[3];
  const float* w1  = (const float*)d_in[4];
  const float* b1  = (const float*)d_in[5];
  const float* w2  = (const float*)d_in[6];
  const float* b2  = (const float*)d_in[7];
  const float* mw1 = (const float*)d_in[8];
  const float* mb1 = (const float*)d_in[9];
  const float* mw2 = (const float*)d_in[10];
  const float* mb2 = (const float*)d_in[11];
  float* out = (float*)d_out;

  // workspace carving (bytes)
  char* p = (char*)d_ws;
  unsigned short* embbf = (unsigned short*)p; p += (size_t)BB * LL * KP * 2;  // 41.9 MB
  unsigned short* w1s2  = (unsigned short*)p; p += (size_t)10 * 256 * 4 * 16; // 160 KB
  float* mw1eff = (float*)p; p += (size_t)900 * HH * 4;                       // 720 KB
  float* spart  = (float*)p; p += (size_t)8 * BB * DD * 4;
  float* opart  = (float*)p; p += (size_t)8 * BB * DD * 4;
  float* avpart = (float*)p; p += (size_t)8 * BB * DD * 4;
  float* semb   = (float*)p; p += (size_t)BB * DD * 4;
  float* oemb   = (float*)p; p += (size_t)BB * DD * 4;
  float* preh   = (float*)p; p += (size_t)BB * HH * 4;
  float* scores = (float*)p; p += (size_t)BB * LL * 4;
  float* p1     = (float*)p; p += (size_t)18 * BB * HH * 4;                   // 1.84 MB

  gather_pool<<<dim3(1768), dim3(256), 0, stream>>>(
      words, spos, opos, tab, w1, mw1, embbf, w1s2, mw1eff, spart, opart);
  combine_preh<<<dim3(BB), dim3(320), 0, stream>>>(
      spart, opart, w1, b1, semb, oemb, preh);
  scores_mfma<<<dim3(BB * 8), dim3(256), 0, stream>>>(
      embbf, w1s2, preh, w2, b2, scores);
  pv_sm<<<dim3(BB * 8), dim3(256), 0, stream>>>(scores, embbf, avpart);
  mlp1p<<<dim3(288), dim3(256), 0, stream>>>(avpart, semb, oemb, mw1eff, p1);
  mlp2f<<<dim3(BB), dim3(256), 0, stream>>>(p1, mb1, mw2, mb2, out);
}

// Round 5
// 201.971 us; speedup vs baseline: 1.9350x; 1.0240x over previous
//
#include <hip/hip_runtime.h>
#include <hip/hip_bf16.h>

#define BB 128
#define LL 512
#define DD 300
#define HH 200
#define VV 50000
#define KP 320           // K padded (10 chunks of 32)
#define NEGBIG 1e12f

typedef __attribute__((ext_vector_type(8))) short bf16x8;
typedef __attribute__((ext_vector_type(4))) float f32x4;

__device__ __forceinline__ float bf2f(unsigned short u) {
  union { unsigned int i; float f; } v; v.i = ((unsigned int)u) << 16; return v.f;
}
__device__ __forceinline__ unsigned short f2bf(float f) {
  union { float f; unsigned int i; } v; v.f = f;
  unsigned int r = v.i + 0x7FFFu + ((v.i >> 16) & 1u);  // RNE (finite inputs)
  return (unsigned short)(r >> 16);
}

typedef const __attribute__((address_space(1))) unsigned int ga_u32;
typedef __attribute__((address_space(3))) unsigned int lds_u32;
__device__ __forceinline__ void gl_lds16(const void* g, void* l) {
  __builtin_amdgcn_global_load_lds((ga_u32*)g, (lds_u32*)l, 16, 0, 0);
}

// ---------------------------------------------------------------------------
// Kernel 1: fused gather + bf16 convert + emb_bf materialize + pool partials.
// Blocks 0..1023: (b, ch) tiles of 64 rows. Blocks 1024..1063: w1s2 prep.
// Blocks 1064..1767: mw1eff prep (layer-1 fold: mw1eff[k]=mw1[k]+mw1[300+k]
// for k<300 since x=[sattn,sattn,semb,oemb] duplicates sattn).
// ---------------------------------------------------------------------------
__global__ __launch_bounds__(256) void gather_pool(
    const int* __restrict__ words, const int* __restrict__ spos,
    const int* __restrict__ opos, const float* __restrict__ tab,
    const float* __restrict__ w1, const float* __restrict__ mw1,
    unsigned short* __restrict__ embbf, unsigned short* __restrict__ w1s2,
    float* __restrict__ mw1eff,
    float* __restrict__ spart, float* __restrict__ opart) {
  int blk = blockIdx.x;
  int tid = threadIdx.x;

  if (blk >= 1064) {
    // ---- mw1eff prep: eff-K = 900 (sattn 0..299, semb 300..599, oemb 600..899)
    int idx = (blk - 1064) * 256 + tid;
    if (idx < 900 * HH) {
      int k = idx / HH, h = idx - k * HH;
      float v;
      if (k < 300) v = mw1[(size_t)k * HH + h] + mw1[(size_t)(300 + k) * HH + h];
      else v = mw1[(size_t)(k + 300) * HH + h];   // semb / oemb regions
      mw1eff[idx] = v;
    }
    return;
  }
  if (blk >= 1024) {
    // ---- w1s2 prep: 40 blocks x 256 threads = 10240 c16 units
    int u = (blk - 1024) * 256 + tid;
    int kc = u >> 10;
    int rem = u & 1023;
    int row = rem >> 2, c16 = rem & 3;
    int s = (row ^ (row >> 2)) & 3;
    int kb = kc * 32 + ((c16 ^ s) << 3);
    bf16x8 o;
#pragma unroll
    for (int j = 0; j < 8; ++j) {
      int k = kb + j;
      float v = (k < DD && row < HH) ? w1[(size_t)k * HH + row] : 0.f;
      o[j] = (short)f2bf(v);
    }
    *(bf16x8*)(w1s2 + (size_t)u * 8) = o;
    return;
  }

  int b = blk >> 3, ch = blk & 7, l0 = ch * 64;
  __shared__ int wd[64], sm[64], om[64];
  __shared__ unsigned short tile[64 * 328];   // row stride 328 (bank-friendly)
  if (tid < 64) {
    wd[tid] = words[b * LL + l0 + tid];
    sm[tid] = spos[b * LL + l0 + tid];
    om[tid] = opos[b * LL + l0 + tid];
  }
  __syncthreads();

  // gather + convert: 4 threads per row, 64B-coalesced float4 reads
  {
    int r = tid >> 2, qg = tid & 3;
    const float* srow = tab + (size_t)wd[r] * DD;
    unsigned short* trow = tile + r * 328;
#pragma unroll
    for (int i = 0; i < 19; ++i) {
      int q = qg + 4 * i;
      if (q < 75) {
        float4 v = *(const float4*)(srow + q * 4);
        ushort4 o;
        o.x = f2bf(v.x); o.y = f2bf(v.y); o.z = f2bf(v.z); o.w = f2bf(v.w);
        *(ushort4*)(trow + q * 4) = o;
      }
    }
    // zero-pad cols 300..327
    if (qg == 0) {
#pragma unroll
      for (int c = 300; c < 328; c += 4) {
        ushort4 z; z.x = z.y = z.z = z.w = 0;
        *(ushort4*)(trow + c) = z;
      }
    }
  }
  __syncthreads();

  // stream LDS tile -> emb_bf (linear [64][320] bf16 rows)
  {
    char* embdst = (char*)embbf + (size_t)(b * LL + l0) * 640;
#pragma unroll
    for (int j = 0; j < 10; ++j) {
      int g16 = j * 256 + tid;
      int row = g16 / 40, cb = g16 % 40;
      uint4 v = *(const uint4*)((const char*)tile + row * 656 + cb * 16);
      *(uint4*)(embdst + (size_t)g16 * 16) = v;
    }
  }

  // pool partials from LDS (keep where pos==0); unroll 8 for LDS-read ILP
  if (tid < 150) {
    float s0 = -NEGBIG, s1 = -NEGBIG, o0 = -NEGBIG, o1 = -NEGBIG;
#pragma unroll 8
    for (int r = 0; r < 64; ++r) {
      unsigned int v = *(const unsigned int*)((const char*)tile + r * 656 + tid * 4);
      float v0 = bf2f((unsigned short)(v & 0xffff));
      float v1 = bf2f((unsigned short)(v >> 16));
      if (sm[r] == 0) { s0 = fmaxf(s0, v0); s1 = fmaxf(s1, v1); }
      if (om[r] == 0) { o0 = fmaxf(o0, v0); o1 = fmaxf(o1, v1); }
    }
    size_t base = (size_t)(ch * BB + b) * DD + tid * 2;
    *(float2*)(spart + base) = make_float2(s0, s1);
    *(float2*)(opart + base) = make_float2(o0, o1);
  }
}

// ---------------------------------------------------------------------------
// Kernel 2: combine pool partials + fused preh. Grid B, block 320.
// preh[b,h] = b1[h] + sum_d semb[b,d] * w1[(300+d)*200+h]
// ---------------------------------------------------------------------------
__global__ __launch_bounds__(320) void combine_preh(
    const float* __restrict__ spart, const float* __restrict__ opart,
    const float* __restrict__ w1, const float* __restrict__ b1,
    float* __restrict__ semb, float* __restrict__ oemb,
    float* __restrict__ preh) {
  int b = blockIdx.x, t = threadIdx.x;
  __shared__ float se[DD];
  if (t < DD) {
    float s = -NEGBIG, o = -NEGBIG;
    for (int ch = 0; ch < 8; ++ch) {
      size_t base = (size_t)(ch * BB + b) * DD + t;
      s = fmaxf(s, spart[base]);
      o = fmaxf(o, opart[base]);
    }
    semb[(size_t)b * DD + t] = s;
    oemb[(size_t)b * DD + t] = o;
    se[t] = s;
  }
  __syncthreads();
  if (t < HH) {
    const float* w1b = w1 + (size_t)DD * HH + t;
    float acc = b1[t];
#pragma unroll 10
    for (int d = 0; d < DD; ++d) acc += se[d] * w1b[(size_t)d * HH];
    preh[(size_t)b * HH + t] = acc;
  }
}

// ---------------------------------------------------------------------------
// Kernel 3: scores via MFMA, LDS-staged. Grid B*8 (64-pos tiles), block 256.
// A: full 64x320 tile staged once via global_load_lds, col16 XOR (row&7) swz.
// B: w1s2 chunk (16KB, pre-swizzled, chunk-major) double-buffered, 2-phase.
// ---------------------------------------------------------------------------
__global__ __launch_bounds__(256) void scores_mfma(
    const unsigned short* __restrict__ embbf,
    const unsigned short* __restrict__ w1s2, const float* __restrict__ preh,
    const float* __restrict__ w2, const float* __restrict__ b2,
    float* __restrict__ scores) {
  int tile = blockIdx.x;
  int b = tile >> 3, l0 = (tile & 7) * 64;
  int tid = threadIdx.x;
  int w = tid >> 6, lane = tid & 63;
  int lr = lane & 15, lq = lane >> 4;

  __shared__ unsigned short ldsA[64 * 320];        // 40960 B, swizzled
  __shared__ unsigned short ldsB[2][256 * 32];     // 2 x 16384 B

  const char* embbase = (const char*)embbf + (size_t)(b * LL + l0) * 640;
  int wbase16 = (w << 6);   // wave-uniform lane-0 16B-unit index offset

  // ---- prologue: stage A (10 instr/thread) + B chunk 0 (4 instr/thread)
#pragma unroll
  for (int j = 0; j < 10; ++j) {
    int d16 = j * 256 + tid;
    int row = d16 / 40, c = d16 % 40;
    const void* src = embbase + row * 640 + (c ^ (row & 7)) * 16;
    void* dst = (char*)ldsA + (size_t)(j * 256 + wbase16) * 16;
    gl_lds16(src, dst);
  }
  {
    const char* srcb = (const char*)w1s2;  // kc = 0
#pragma unroll
    for (int j = 0; j < 4; ++j)
      gl_lds16(srcb + (size_t)(j * 256 + tid) * 16,
               (char*)&ldsB[0][0] + (size_t)(j * 256 + wbase16) * 16);
  }
  __syncthreads();   // drains vmcnt(0) + barrier

  f32x4 acc[13];
#pragma unroll
  for (int nt = 0; nt < 13; ++nt) acc[nt] = (f32x4){0.f, 0.f, 0.f, 0.f};

  int slr = (lr ^ (lr >> 2)) & 3;
  const char* aAddr = (const char*)ldsA + (w * 16 + lr) * 640;
  int cur = 0;
  for (int kc = 0; kc < 10; ++kc) {
    if (kc < 9) {   // stage next chunk into the other buffer
      const char* srcb = (const char*)w1s2 + (size_t)(kc + 1) * 16384;
#pragma unroll
      for (int j = 0; j < 4; ++j)
        gl_lds16(srcb + (size_t)(j * 256 + tid) * 16,
                 (char*)&ldsB[cur ^ 1][0] + (size_t)(j * 256 + wbase16) * 16);
    }
    bf16x8 a = *(const bf16x8*)(aAddr + (((kc * 4 + lq) ^ (lr & 7)) * 16));
    const char* bbase = (const char*)&ldsB[cur][0] + lr * 64 + ((lq ^ slr) * 16);
#pragma unroll
    for (int nt = 0; nt < 13; ++nt) {
      bf16x8 bv = *(const bf16x8*)(bbase + nt * 16 * 64);
      acc[nt] = __builtin_amdgcn_mfma_f32_16x16x32_bf16(a, bv, acc[nt], 0, 0, 0);
    }
    __syncthreads();   // vmcnt(0) + lgkmcnt(0) + barrier: next buffer ready
    cur ^= 1;
  }

  // ---- epilogue: score = b2 + sum_h w2[h]*tanh(acc + preh[b,h])
  float w2v[13], ph[13];
#pragma unroll
  for (int nt = 0; nt < 13; ++nt) {
    int h = nt * 16 + lr;
    bool v = (h < HH);
    w2v[nt] = v ? w2[h] : 0.f;
    ph[nt] = v ? preh[(size_t)b * HH + h] : 0.f;
  }
  float part[4] = {0.f, 0.f, 0.f, 0.f};
#pragma unroll
  for (int nt = 0; nt < 13; ++nt) {
#pragma unroll
    for (int r = 0; r < 4; ++r)
      part[r] += w2v[nt] * tanhf(acc[nt][r] + ph[nt]);
  }
#pragma unroll
  for (int off = 8; off; off >>= 1) {
#pragma unroll
    for (int r = 0; r < 4; ++r) part[r] += __shfl_xor(part[r], off, 16);
  }
  if (lr == 0) {
    float bb = b2[0];
#pragma unroll
    for (int r = 0; r < 4; ++r) {
      int pos = l0 + w * 16 + lq * 4 + r;
      scores[(size_t)b * LL + pos] = part[r] + bb;
    }
  }
}

// ---------------------------------------------------------------------------
// Kernel 4: fused softmax + PV partials. Grid B*8, block 256.
// Accumulate phase: 240 threads, 16B bf16x8 loads, 6-way row split (chain
// depth 64 -> 11), LDS partial-combine. Cols 300..319 of embbf are zeros.
// ---------------------------------------------------------------------------
__global__ __launch_bounds__(256) void pv_sm(
    const float* __restrict__ scores, const unsigned short* __restrict__ embbf,
    float* __restrict__ avpart) {
  int blk = blockIdx.x;
  int b = blk >> 3, ch = blk & 7, l0 = ch * 64;
  int tid = threadIdx.x;
  __shared__ float red[16];
  __shared__ float at[64];
  __shared__ float pacc[6][40][8];

  float s0 = scores[(size_t)b * LL + tid];
  float s1 = scores[(size_t)b * LL + 256 + tid];
  float m = fmaxf(s0, s1);
#pragma unroll
  for (int off = 32; off; off >>= 1) m = fmaxf(m, __shfl_xor(m, off, 64));
  if ((tid & 63) == 0) red[tid >> 6] = m;
  __syncthreads();
  float M = fmaxf(fmaxf(red[0], red[1]), fmaxf(red[2], red[3]));
  float e = expf(s0 - M) + expf(s1 - M);
#pragma unroll
  for (int off = 32; off; off >>= 1) e += __shfl_xor(e, off, 64);
  if ((tid & 63) == 0) red[8 + (tid >> 6)] = e;
  __syncthreads();
  float S = red[8] + red[9] + red[10] + red[11];
  if (tid < 64) at[tid] = expf(scores[(size_t)b * LL + l0 + tid] - M) / S;
  __syncthreads();

  int u = tid % 40, g = tid / 40;   // g in 0..5 for tid<240
  if (tid < 240) {
    float facc[8] = {0.f, 0.f, 0.f, 0.f, 0.f, 0.f, 0.f, 0.f};
    const char* base = (const char*)embbf + (size_t)(b * LL + l0) * 640 + u * 16;
#pragma unroll 4
    for (int r = g; r < 64; r += 6) {
      bf16x8 v = *(const bf16x8*)(base + (size_t)r * 640);
      float wgt = at[r];
#pragma unroll
      for (int q = 0; q < 8; ++q) facc[q] += wgt * bf2f((unsigned short)v[q]);
    }
#pragma unroll
    for (int q = 0; q < 8; ++q) pacc[g][u][q] = facc[q];
  }
  __syncthreads();
  if (tid < 160) {
    int u2 = tid >> 2, j = tid & 3;
    int d = u2 * 8 + j * 2;
    if (d < DD) {
      float v0 = 0.f, v1 = 0.f;
#pragma unroll
      for (int gg = 0; gg < 6; ++gg) {
        v0 += pacc[gg][u2][j * 2];
        v1 += pacc[gg][u2][j * 2 + 1];
      }
      *(float2*)(avpart + (size_t)(ch * BB + b) * DD + d) = make_float2(v0, v1);
    }
  }
}

// ---------------------------------------------------------------------------
// Kernel 5: MLP layer-1 partials over mw1eff (eff-K = 900).
// Grid 288 = (bc 0..15)*(kc 0..17), block 256. Each block: 8 b x 200 h x 50 k.
// ---------------------------------------------------------------------------
__global__ __launch_bounds__(256) void mlp1p(
    const float* __restrict__ avpart, const float* __restrict__ semb,
    const float* __restrict__ oemb, const float* __restrict__ mw1eff,
    float* __restrict__ p1) {
  int bc = blockIdx.x / 18, kc = blockIdx.x % 18;
  int tid = threadIdx.x;
  __shared__ float xT[50][8];
  for (int idx = tid; idx < 400; idx += 256) {
    int bb = idx & 7, kk = idx >> 3;
    int k = kc * 50 + kk;
    int b = bc * 8 + bb;
    int reg = k / 300, d = k - reg * 300;
    float v;
    if (reg == 0) {
      v = 0.f;
#pragma unroll
      for (int chh = 0; chh < 8; ++chh)
        v += avpart[(size_t)(chh * BB + b) * DD + d];
    } else if (reg == 1) {
      v = semb[(size_t)b * DD + d];
    } else {
      v = oemb[(size_t)b * DD + d];
    }
    xT[kk][bb] = v;
  }
  __syncthreads();
  if (tid >= HH) return;
  const float* wp = mw1eff + (size_t)(kc * 50) * HH + tid;
  float acc[8] = {0.f, 0.f, 0.f, 0.f, 0.f, 0.f, 0.f, 0.f};
#pragma unroll 5
  for (int kk = 0; kk < 50; ++kk) {
    float wv = wp[(size_t)kk * HH];
#pragma unroll
    for (int bb = 0; bb < 8; ++bb) acc[bb] += xT[kk][bb] * wv;
  }
#pragma unroll
  for (int bb = 0; bb < 8; ++bb)
    p1[((size_t)kc * BB + bc * 8 + bb) * HH + tid] = acc[bb];
}

// ---------------------------------------------------------------------------
// Kernel 6: MLP combine + relu + layer-2 + relu. Grid B (one b each), blk 256.
// ---------------------------------------------------------------------------
__global__ __launch_bounds__(256) void mlp2f(
    const float* __restrict__ p1, const float* __restrict__ mb1,
    const float* __restrict__ mw2, const float* __restrict__ mb2,
    float* __restrict__ out) {
  int b = blockIdx.x, tid = threadIdx.x;
  __shared__ float h1[HH];
  if (tid < HH) {
    float s = mb1[tid];
#pragma unroll
    for (int kc = 0; kc < 18; ++kc)
      s += p1[((size_t)kc * BB + b) * HH + tid];
    h1[tid] = fmaxf(s, 0.f);
  }
  __syncthreads();
  if (tid >= HH) return;
  const float* wp = mw2 + tid;
  float acc = mb2[tid];
#pragma unroll 8
  for (int k = 0; k < HH; ++k) acc += h1[k] * wp[(size_t)k * HH];
  out[(size_t)b * HH + tid] = fmaxf(acc, 0.f);
}

// ---------------------------------------------------------------------------
extern "C" void kernel_launch(void* const* d_in, const int* in_sizes, int n_in,
                              void* d_out, int out_size, void* d_ws, size_t ws_size,
                              hipStream_t stream) {
  const int* words = (const int*)d_in[0];
  const int* spos  = (const int*)d_in[1];
  const int* opos  = (const int*)d_in[2];
  const float* tab = (const float*)d_in[3];
  const float* w1  = (const float*)d_in[4];
  const float* b1  = (const float*)d_in[5];
  const float* w2  = (const float*)d_in[6];
  const float* b2  = (const float*)d_in[7];
  const float* mw1 = (const float*)d_in[8];
  const float* mb1 = (const float*)d_in[9];
  const float* mw2 = (const float*)d_in[10];
  const float* mb2 = (const float*)d_in[11];
  float* out = (float*)d_out;

  // workspace carving (bytes)
  char* p = (char*)d_ws;
  unsigned short* embbf = (unsigned short*)p; p += (size_t)BB * LL * KP * 2;  // 41.9 MB
  unsigned short* w1s2  = (unsigned short*)p; p += (size_t)10 * 256 * 4 * 16; // 160 KB
  float* mw1eff = (float*)p; p += (size_t)900 * HH * 4;                       // 720 KB
  float* spart  = (float*)p; p += (size_t)8 * BB * DD * 4;
  float* opart  = (float*)p; p += (size_t)8 * BB * DD * 4;
  float* avpart = (float*)p; p += (size_t)8 * BB * DD * 4;
  float* semb   = (float*)p; p += (size_t)BB * DD * 4;
  float* oemb   = (float*)p; p += (size_t)BB * DD * 4;
  float* preh   = (float*)p; p += (size_t)BB * HH * 4;
  float* scores = (float*)p; p += (size_t)BB * LL * 4;
  float* p1     = (float*)p; p += (size_t)18 * BB * HH * 4;                   // 1.84 MB

  gather_pool<<<dim3(1768), dim3(256), 0, stream>>>(
      words, spos, opos, tab, w1, mw1, embbf, w1s2, mw1eff, spart, opart);
  combine_preh<<<dim3(BB), dim3(320), 0, stream>>>(
      spart, opart, w1, b1, semb, oemb, preh);
  scores_mfma<<<dim3(BB * 8), dim3(256), 0, stream>>>(
      embbf, w1s2, preh, w2, b2, scores);
  pv_sm<<<dim3(BB * 8), dim3(256), 0, stream>>>(scores, embbf, avpart);
  mlp1p<<<dim3(288), dim3(256), 0, stream>>>(avpart, semb, oemb, mw1eff, p1);
  mlp2f<<<dim3(BB), dim3(256), 0, stream>>>(p1, mb1, mw2, mb2, out);
}